// Round 6
// baseline (288.859 us; speedup 1.0000x reference)
//
#include <hip/hip_runtime.h>
#include <math.h>

// ws layout (float offsets)
#define WS_KV   0        // 300: Wk @ u   (16B aligned)
#define WS_C0   300      // bk . u
#define WS_C1   301      // bq . u2
#define WS_Y    304      // 300: y = Wq @ u2
#define WS_ROW  2048     // 256*4: {mem_len_f, startf, endf, qb}
#define WS_ACC  4096     // 512*300 partial softmax-weighted sums
#define WS_VSP  161792   // 512*300 partial v_s sums
#define WS_SCAL 315392   // 512*2: {denom_partial, mem_len_f}

__device__ __forceinline__ float wred(float v) {
#pragma unroll
    for (int off = 32; off > 0; off >>= 1) v += __shfl_xor(v, off);
    return v;
}

// fast tanh via hardware exp; error way under the 6.7e-3 threshold
__device__ __forceinline__ float ftanh(float z) {
    float t = __expf(2.f * z);
    return (t - 1.f) / (t + 1.f);
}

// ---------------------------------------------------------------------------
// k_prep: grid 302 x 64 (grid-parallel; single-block fusion measured 71us)
//  blocks 0..299: kv[j] = Wk row j . u ; y[j] = Wq row j . u2
//  block 300: c0 = bk.u ; block 301: c1 = bq.u2
// ---------------------------------------------------------------------------
__global__ __launch_bounds__(64) void k_prep(
    const float* __restrict__ Wk, const float* __restrict__ bk,
    const float* __restrict__ Wq, const float* __restrict__ bq,
    const float* __restrict__ wmlp, float* __restrict__ ws)
{
    const int lane = threadIdx.x;
    const int j = blockIdx.x;
    const float* u  = wmlp;
    const float* u2 = wmlp + 300;
    if (j < 300) {
        float pk = 0.f, pq = 0.f;
#pragma unroll
        for (int m = 0; m < 5; ++m) {
            int idx = lane + 64 * m;
            if (idx < 300) {
                pk += Wk[j * 300 + idx] * u[idx];
                pq += Wq[j * 300 + idx] * u2[idx];
            }
        }
        pk = wred(pk); pq = wred(pq);
        if (lane == 0) { ws[WS_KV + j] = pk; ws[WS_Y + j] = pq; }
    } else if (j == 300) {
        float p = 0.f;
#pragma unroll
        for (int m = 0; m < 5; ++m) { int idx = lane + 64 * m; if (idx < 300) p += bk[idx] * u[idx]; }
        p = wred(p);
        if (lane == 0) ws[WS_C0] = p;
    } else {
        float p = 0.f;
#pragma unroll
        for (int m = 0; m < 5; ++m) { int idx = lane + 64 * m; if (idx < 300) p += bq[idx] * u2[idx]; }
        p = wred(p);
        if (lane == 0) ws[WS_C1] = p;
    }
}

// ---------------------------------------------------------------------------
// k_row: grid 256 x 512. Per-batch-row scalars + PER-BATCH x-chain:
//   x0 = asp_e ; x_{h+1}[j] = sum_i x_h[i]*Wx[i][j] (3 hops, Wx L2-resident)
//   qb = x3 . y + c0 + c1
// Replaces the 3 sequential grid-wide k_hop launches (R5 structure).
// ---------------------------------------------------------------------------
__global__ __launch_bounds__(512) void k_row(
    const int* __restrict__ text, const int* __restrict__ aspect,
    const int* __restrict__ left, const float* __restrict__ embed,
    const float* __restrict__ Wx, float* __restrict__ ws)
{
    const int b = blockIdx.x;
    const int t = threadIdx.x, wv = t >> 6, lane = t & 63;

    __shared__ int   atoks[8];
    __shared__ int   cntW[8];
    __shared__ float qp[5];
    __shared__ float xA[300], xB[300];
    __shared__ int   lCnt, aCnt;

    const int tk = text[b * 512 + t];
    {
        unsigned long long m = __ballot(tk != 0);
        if (lane == 0) cntW[wv] = __popcll(m);
    }
    if (wv == 0) {
        unsigned long long m = __ballot(left[b * 64 + lane] != 0);
        if (lane == 0) lCnt = __popcll(m);
    }
    if (wv == 1) {
        int ak = (lane < 8) ? aspect[b * 8 + lane] : 0;
        if (lane < 8) atoks[lane] = ak;
        unsigned long long m = __ballot(lane < 8 && ak != 0);
        if (lane == 0) aCnt = __popcll(m);
    }
    __syncthreads();

    // x0 = asp_e
    if (t < 300) {
        float s = 0.f;
#pragma unroll
        for (int a = 0; a < 8; ++a) s += embed[(size_t)atoks[a] * 300 + t];
        xA[t] = s / (float)aCnt;
    }
    __syncthreads();

    // 3 hops: row-vector @ Wx. Thread t computes column t (coalesced across t).
#pragma unroll
    for (int hop = 0; hop < 3; ++hop) {
        const float* src = (hop & 1) ? xB : xA;
        float* dst = (hop & 1) ? xA : xB;
        if (t < 300) {
            float acc = 0.f;
#pragma unroll 4
            for (int i = 0; i < 300; ++i) acc += src[i] * Wx[i * 300 + t];
            dst[t] = acc;
        }
        __syncthreads();
    }
    // final x3 in xB

    if (wv < 5) {
        float v = 0.f;
        if (t < 300) v = xB[t] * ws[WS_Y + t];
        v = wred(v);
        if (lane == 0) qp[wv] = v;
    }
    __syncthreads();

    if (t == 0) {
        int ml = 0;
#pragma unroll
        for (int w = 0; w < 8; ++w) ml += cntW[w];
        float q = qp[0] + qp[1] + qp[2] + qp[3] + qp[4]
                + ws[WS_C0] + ws[WS_C1];
        ws[WS_ROW + b * 4 + 0] = (float)ml;
        ws[WS_ROW + b * 4 + 1] = (float)(lCnt - aCnt);
        ws[WS_ROW + b * 4 + 2] = (float)lCnt;
        ws[WS_ROW + b * 4 + 3] = q;
    }
}

// ---------------------------------------------------------------------------
// k_main: grid 512 x 512. Block (b, half): 256 tokens of batch b.
// 8 waves x 32 tokens, ILP-4. launch_bounds(512,2): 128-VGPR cap, no spills.
// ((512,4) forced 64 VGPRs -> 121 MB of scratch spills, 94us. DO NOT.)
// ---------------------------------------------------------------------------
__global__ __launch_bounds__(512, 2) void k_main(
    const int* __restrict__ text, const float* __restrict__ embed,
    float* __restrict__ ws)
{
    const int bid = blockIdx.x;
    const int b = bid >> 1, half = bid & 1;
    const int t = threadIdx.x, wv = t >> 6, lane = t & 63;

    __shared__ int   toksS[256];
    __shared__ __align__(16) float accW[8 * 300];
    __shared__ __align__(16) float vsW[8 * 300];
    __shared__ float denomW[8], sc[4];

    if (t < 256) toksS[t] = text[b * 512 + half * 256 + t];
    if (t >= 256 && t < 260) sc[t - 256] = ws[WS_ROW + b * 4 + (t - 256)];
    __syncthreads();
    const float mem_len_f = sc[0], startf = sc[1], endf = sc[2], qb = sc[3];
    const float inv_ml = 1.f / mem_len_f;

    const float4* kv4  = (const float4*)(ws + WS_KV);
    const float4* emb4 = (const float4*)embed;   // row = tok*75 float4s
    const bool hasB = (lane < 11);
    const float4 kva = kv4[lane];
    const float4 kvb = hasB ? kv4[64 + lane] : make_float4(0.f, 0.f, 0.f, 0.f);
    const float4 fz = make_float4(0.f, 0.f, 0.f, 0.f);

    float4 accA = fz, accB = fz, vsA = fz, vsB = fz;
    float denom = 0.f;
    const float posbase = (float)(half * 256);

    for (int it = 0; it < 8; ++it) {
        const int base = wv * 32 + 4 * it;
        int rr[4];
#pragma unroll
        for (int k = 0; k < 4; ++k) rr[k] = toksS[base + k] * 75;
        float4 A[4], Bv[4];
#pragma unroll
        for (int k = 0; k < 4; ++k) A[k] = emb4[rr[k] + lane];
#pragma unroll
        for (int k = 0; k < 4; ++k) Bv[k] = hasB ? emb4[rr[k] + 64 + lane] : fz;

        float pd[4];
#pragma unroll
        for (int k = 0; k < 4; ++k)
            pd[k] = A[k].x*kva.x + A[k].y*kva.y + A[k].z*kva.z + A[k].w*kva.w
                  + Bv[k].x*kvb.x + Bv[k].y*kvb.y + Bv[k].z*kvb.z + Bv[k].w*kvb.w;
#pragma unroll
        for (int off = 32; off > 0; off >>= 1) {
#pragma unroll
            for (int k = 0; k < 4; ++k) pd[k] += __shfl_xor(pd[k], off);
        }

#pragma unroll
        for (int k = 0; k < 4; ++k) {
            const float f = posbase + (float)(base + k);
            float lv = (f < startf) ? (startf - f) : ((f <= endf) ? 0.f : (f - endf));
            float wgt = 1.f - lv * inv_ml;
            wgt = (f < mem_len_f) ? wgt : 0.f;
            const float p = __expf(ftanh(wgt * pd[k] + qb));
            const float pw = p * wgt;
            accA.x += pw * A[k].x;  accA.y += pw * A[k].y;
            accA.z += pw * A[k].z;  accA.w += pw * A[k].w;
            accB.x += pw * Bv[k].x; accB.y += pw * Bv[k].y;
            accB.z += pw * Bv[k].z; accB.w += pw * Bv[k].w;
            vsA.x += A[k].x;  vsA.y += A[k].y;  vsA.z += A[k].z;  vsA.w += A[k].w;
            vsB.x += Bv[k].x; vsB.y += Bv[k].y; vsB.z += Bv[k].z; vsB.w += Bv[k].w;
            denom += p;
        }
    }

    *(float4*)&accW[wv * 300 + 4 * lane] = accA;
    *(float4*)&vsW [wv * 300 + 4 * lane] = vsA;
    if (hasB) {
        *(float4*)&accW[wv * 300 + 256 + 4 * lane] = accB;
        *(float4*)&vsW [wv * 300 + 256 + 4 * lane] = vsB;
    }
    if (lane == 0) denomW[wv] = denom;
    __syncthreads();

    if (t < 300) {
        float ds = 0.f;
#pragma unroll
        for (int w = 0; w < 8; ++w) ds += denomW[w];
        float ms = 0.f, vs = 0.f;
#pragma unroll
        for (int w = 0; w < 8; ++w) { ms += accW[w * 300 + t]; vs += vsW[w * 300 + t]; }
        ws[WS_ACC + bid * 300 + t] = ms;
        ws[WS_VSP + bid * 300 + t] = vs;
        if (t == 0) { ws[WS_SCAL + bid * 2] = ds; ws[WS_SCAL + bid * 2 + 1] = mem_len_f; }
    }
}

// ---------------------------------------------------------------------------
// k_tail: grid 256 x 960. Merge 2 half-partials + 3 chained GEMVs + softmax.
// ---------------------------------------------------------------------------
__global__ __launch_bounds__(960) void k_tail(
    const float* __restrict__ Wk, const float* __restrict__ bk,
    const float* __restrict__ Wproj, const float* __restrict__ bproj,
    const float* __restrict__ Wm, const float* __restrict__ bm,
    const float* __restrict__ Wd, const float* __restrict__ bd,
    float* __restrict__ out, const float* __restrict__ ws)
{
    const int t = threadIdx.x;
    const int b = blockIdx.x;
    const int seg = t / 320, j = t - seg * 320;

    __shared__ float A[300], T[300], VSs[300], part[900], vms[300], lg[3];

    if (t < 300) {
        const int p0 = (b * 2) * 300 + t;
        float a = ws[WS_ACC + p0] + ws[WS_ACC + p0 + 300];
        float v = ws[WS_VSP + p0] + ws[WS_VSP + p0 + 300];
        const int s0 = b * 4;
        float d  = ws[WS_SCAL + s0] + ws[WS_SCAL + s0 + 2];
        float ml = ws[WS_SCAL + s0 + 1];
        A[t]   = a / d;
        VSs[t] = v / ml;
    }
    __syncthreads();

    if (j < 300) {
        const int k0 = seg * 100;
        float acc = 0.f;
#pragma unroll 10
        for (int i = 0; i < 100; ++i) acc += A[k0 + i] * Wk[(k0 + i) * 300 + j];
        part[seg * 300 + j] = acc;
    }
    __syncthreads();
    if (t < 300) T[t] = part[t] + part[300 + t] + part[600 + t] + bk[t];
    __syncthreads();

    if (j < 300) {
        const int k0 = seg * 100;
        float acc = 0.f;
#pragma unroll 10
        for (int i = 0; i < 100; ++i) acc += T[k0 + i] * Wproj[(k0 + i) * 300 + j];
        part[seg * 300 + j] = acc;
    }
    __syncthreads();
    if (t < 300) A[t] = part[t] + part[300 + t] + part[600 + t] + bproj[t] + VSs[t];
    __syncthreads();

    if (j < 300) {
        const int k0 = seg * 100;
        float acc = 0.f;
#pragma unroll 10
        for (int i = 0; i < 100; ++i) acc += A[k0 + i] * Wm[(k0 + i) * 300 + j];
        part[seg * 300 + j] = acc;
    }
    __syncthreads();
    if (t < 300) vms[t] = tanhf(part[t] + part[300 + t] + part[600 + t] + bm[t]);
    __syncthreads();

    const int wv = t >> 6, lane = t & 63;
    if (wv < 3) {
        float p = 0.f;
#pragma unroll
        for (int k = 0; k < 5; ++k) { int d = lane + 64 * k; if (d < 300) p += vms[d] * Wd[d * 3 + wv]; }
        p = wred(p);
        if (lane == 0) lg[wv] = p + bd[wv];
    }
    __syncthreads();
    if (t == 0) {
        float l0 = lg[0], l1 = lg[1], l2 = lg[2];
        float mx = fmaxf(l0, fmaxf(l1, l2));
        float e0 = expf(l0 - mx), e1 = expf(l1 - mx), e2 = expf(l2 - mx);
        float s = e0 + e1 + e2;
        out[b * 3 + 0] = e0 / s;
        out[b * 3 + 1] = e1 / s;
        out[b * 3 + 2] = e2 / s;
    }
}

extern "C" void kernel_launch(void* const* d_in, const int* in_sizes, int n_in,
                              void* d_out, int out_size, void* d_ws, size_t ws_size,
                              hipStream_t stream)
{
    (void)in_sizes; (void)n_in; (void)out_size; (void)ws_size;
    const int*   text   = (const int*)d_in[0];
    const int*   aspect = (const int*)d_in[1];
    const int*   left   = (const int*)d_in[2];
    const float* embed  = (const float*)d_in[3];
    const float* Wx     = (const float*)d_in[4];
    // d_in[5] = Ws : dead code in reference
    const float* Wk     = (const float*)d_in[6];
    const float* bk     = (const float*)d_in[7];
    const float* Wq     = (const float*)d_in[8];
    const float* bq     = (const float*)d_in[9];
    const float* wmlp   = (const float*)d_in[10];
    const float* Wproj  = (const float*)d_in[11];
    const float* bproj  = (const float*)d_in[12];
    const float* Wm     = (const float*)d_in[13];
    const float* bm     = (const float*)d_in[14];
    const float* Wd     = (const float*)d_in[15];
    const float* bd     = (const float*)d_in[16];
    float* out = (float*)d_out;
    float* ws  = (float*)d_ws;

    hipLaunchKernelGGL(k_prep, dim3(302), dim3(64), 0, stream, Wk, bk, Wq, bq, wmlp, ws);
    hipLaunchKernelGGL(k_row, dim3(256), dim3(512), 0, stream, text, aspect, left, embed, Wx, ws);
    hipLaunchKernelGGL(k_main, dim3(512), dim3(512), 0, stream, text, embed, ws);
    hipLaunchKernelGGL(k_tail, dim3(256), dim3(960), 0, stream,
                       Wk, bk, Wproj, bproj, Wm, bm, Wd, bd, out, ws);
}